// Round 16
// baseline (744.242 us; speedup 1.0000x reference)
//
#include <hip/hip_runtime.h>

#define BB 256
#define SS 1024
#define TT 128
#define EN 127          // END state (row EN of trans = -1e4)
#define IMIN -10000.0f
#define L2E 1.4426950408889634f
#define LN2f 0.6931471805599453f

typedef _Float16 half2v __attribute__((ext_vector_type(2)));

__device__ __forceinline__ float fdot2(unsigned a, unsigned b, float c) {
#if __has_builtin(__builtin_amdgcn_fdot2)
    return __builtin_amdgcn_fdot2(__builtin_bit_cast(half2v, a),
                                  __builtin_bit_cast(half2v, b), c, false);
#else
    float d;
    asm("v_dot2_f32_f16 %0, %1, %2, %3" : "=v"(d) : "v"(a), "v"(b), "v"(c));
    return d;
#endif
}
__device__ __forceinline__ unsigned pk16(float a, float b) {
    return __builtin_bit_cast(unsigned, __builtin_amdgcn_cvt_pkrtz(a, b));
}
template<int CTRL>
__device__ __forceinline__ float dpp_mov(float x) {
    return __int_as_float(__builtin_amdgcn_update_dpp(
        0, __float_as_int(x), CTRL, 0xF, 0xF, true));
}
__device__ __forceinline__ float rl(float x, int l) {
    return __int_as_float(__builtin_amdgcn_readlane(__float_as_int(x), l));
}
// wave64 max/sum: 4 DPP stages (16-wide) + 4 readlane + combine.
// NO ds_bpermute (r14 paid 2x ~120cy serial DS on the chain for shfl 16/32).
__device__ __forceinline__ float wavemax(float x) {
    x = fmaxf(x, dpp_mov<0xB1>(x));    // quad xor1
    x = fmaxf(x, dpp_mov<0x4E>(x));    // quad xor2
    x = fmaxf(x, dpp_mov<0x141>(x));   // row_half_mirror (8)
    x = fmaxf(x, dpp_mov<0x140>(x));   // row_mirror (16)
    return fmaxf(fmaxf(rl(x, 0), rl(x, 16)), fmaxf(rl(x, 32), rl(x, 48)));
}
__device__ __forceinline__ float wavesum(float x) {
    x += dpp_mov<0xB1>(x);
    x += dpp_mov<0x4E>(x);
    x += dpp_mov<0x141>(x);
    x += dpp_mov<0x140>(x);
    return (rl(x, 0) + rl(x, 16)) + (rl(x, 32) + rl(x, 48));
}

// Wave-per-batch, NO barriers (r14 architecture, fixed):
// 64 blocks x 4 waves; wave w of block g runs batch 4g+w alone on one SIMD.
// Lane owns rows 2l,2l+1; P as f16 pairs (128 VGPRs); matvec = 128 dot2.
// v (128 f16, 256B/wave) exchanged via per-wave LDS; same-wave DS is
// in-order so write->read needs no wait. Exact wave-max keeps v<=1 (f16
// safe; bookkeeping sh += log2(m) is exact for ANY m, so max errors can't
// bias results). r14 failures fixed: (a) 1 wave/CU + VGPR 188 made the
// compiler split reads into ~4 latency exposures -> launch_bounds(256,1)
// + an asm use of one scalar component per uint4 (16 scalar operands;
// whole-uint4 "v" operands don't compile) forces ONE exposure;
// (b) bpermute shfls replaced by DPP+readlane (VALU only).
__global__ __launch_bounds__(256, 1) void crf_fwd(const float* __restrict__ feats,
                                                  const int* __restrict__ blen,
                                                  const float* __restrict__ trans,
                                                  float* __restrict__ out)
{
    const int tid  = threadIdx.x;
    const int lane = tid & 63;
    const int wv   = tid >> 6;
    const int b    = blockIdx.x * 4 + wv;
    const int r0   = 2 * lane, r1 = 2 * lane + 1;

    __shared__ __align__(16) unsigned vb[4][64];   // per-wave v (f16x2)

    const float* fb = feats + (size_t)b * (SS * TT);
    const int L = blen[b];

    // ---- init: P rows -> f16 (normalized 2^(T2-rm)), row sums ----
    const float* t0 = trans + (size_t)r0 * TT;
    const float* t1 = trans + (size_t)r1 * TT;
    float rm0 = -3.4e38f, rm1 = -3.4e38f;
    #pragma unroll
    for (int k = 0; k < 32; ++k) {
        float4 a = ((const float4*)t0)[k];
        rm0 = fmaxf(rm0, fmaxf(fmaxf(a.x, a.y), fmaxf(a.z, a.w)));
        float4 c = ((const float4*)t1)[k];
        rm1 = fmaxf(rm1, fmaxf(fmaxf(c.x, c.y), fmaxf(c.z, c.w)));
    }
    rm0 *= L2E; rm1 *= L2E;

    unsigned P0[64], P1[64];
    float S0 = 0.f, S1 = 0.f;
    #pragma unroll
    for (int k = 0; k < 32; ++k) {
        float4 a = ((const float4*)t0)[k];
        float e0 = exp2f(fmaf(a.x, L2E, -rm0)), e1 = exp2f(fmaf(a.y, L2E, -rm0));
        float e2 = exp2f(fmaf(a.z, L2E, -rm0)), e3 = exp2f(fmaf(a.w, L2E, -rm0));
        S0 += (e0 + e1) + (e2 + e3);
        P0[2 * k] = pk16(e0, e1); P0[2 * k + 1] = pk16(e2, e3);
        float4 c = ((const float4*)t1)[k];
        float g0 = exp2f(fmaf(c.x, L2E, -rm1)), g1 = exp2f(fmaf(c.y, L2E, -rm1));
        float g2 = exp2f(fmaf(c.z, L2E, -rm1)), g3 = exp2f(fmaf(c.w, L2E, -rm1));
        S1 += (g0 + g1) + (g2 + g3);
        P1[2 * k] = pk16(g0, g1); P1[2 * k + 1] = pk16(g2, g3);
    }

    // exact step 0 (alpha0 = delta on START, col START = -1e4):
    // A1 = f0*L2E + IMIN*L2E + log2(1 + sum_j 2^T2_ij), anchored at
    // rmc = max(rm,0) so row EN (rm = -14427) degrades gracefully (r4 fix).
    float2 f0 = *(const float2*)(fb + r0);
    float rmc0 = fmaxf(rm0, 0.f), rmc1 = fmaxf(rm1, 0.f);
    float A10 = fmaf(f0.x, L2E, (IMIN * L2E) + rmc0 +
                     log2f(fmaf(S0, exp2f(rm0 - rmc0), exp2f(-rmc0))));
    float A11 = fmaf(f0.y, L2E, (IMIN * L2E) + rmc1 +
                     log2f(fmaf(S1, exp2f(rm1 - rmc1), exp2f(-rmc1))));

    float m0 = wavemax(fmaxf(A10, A11));
    float sh = m0;
    float vf0 = exp2f(A10 - m0), vf1 = exp2f(A11 - m0);   // <= 1
    vb[wv][lane] = pk16(vf0, vf1);

    const uint4* vv = (const uint4*)(&vb[wv][0]);
    float2 fcur = *(const float2*)(fb + TT + r0);   // feats[1]

    for (int s = 1; s < L; ++s) {
        // prefetch next feature; pin issue point (use is 1 iter away)
        int sn = (s + 1 < SS) ? s + 1 : SS - 1;
        float2 fnx = *(const float2*)(fb + (size_t)sn * TT + r0);
        asm volatile("" :: "v"(fnx.x), "v"(fnx.y));

        // ef off the LDS critical path (fcur already in regs)
        float ef0 = exp2f(fmaf(fcur.x, L2E, rm0));
        float ef1 = exp2f(fmaf(fcur.y, L2E, rm1));

        // broadcast-read whole v: 16 x ds_read_b128, forced into ONE
        // latency exposure (asm requires one scalar component of each
        // uint4 -> all 16 b128 loads must be complete and co-resident)
        uint4 VA0 = vv[0],  VA1 = vv[1],  VA2 = vv[2],  VA3 = vv[3];
        uint4 VA4 = vv[4],  VA5 = vv[5],  VA6 = vv[6],  VA7 = vv[7];
        uint4 VA8 = vv[8],  VA9 = vv[9],  VA10 = vv[10], VA11 = vv[11];
        uint4 VA12 = vv[12], VA13 = vv[13], VA14 = vv[14], VA15 = vv[15];
        asm volatile("" :: "v"(VA0.x),  "v"(VA1.x),  "v"(VA2.x),  "v"(VA3.x),
                           "v"(VA4.x),  "v"(VA5.x),  "v"(VA6.x),  "v"(VA7.x),
                           "v"(VA8.x),  "v"(VA9.x),  "v"(VA10.x), "v"(VA11.x),
                           "v"(VA12.x), "v"(VA13.x), "v"(VA14.x), "v"(VA15.x));

        float a0 = 0.f, a1 = 0.f, a2 = 0.f, a3 = 0.f;
        float b0 = 0.f, b1 = 0.f, b2 = 0.f, b3 = 0.f;
#define DOTS(VA_, p) \
        a0 = fdot2(P0[4*(p)+0], VA_.x, a0); \
        a1 = fdot2(P0[4*(p)+1], VA_.y, a1); \
        a2 = fdot2(P0[4*(p)+2], VA_.z, a2); \
        a3 = fdot2(P0[4*(p)+3], VA_.w, a3); \
        b0 = fdot2(P1[4*(p)+0], VA_.x, b0); \
        b1 = fdot2(P1[4*(p)+1], VA_.y, b1); \
        b2 = fdot2(P1[4*(p)+2], VA_.z, b2); \
        b3 = fdot2(P1[4*(p)+3], VA_.w, b3);
        DOTS(VA0, 0)  DOTS(VA1, 1)  DOTS(VA2, 2)  DOTS(VA3, 3)
        DOTS(VA4, 4)  DOTS(VA5, 5)  DOTS(VA6, 6)  DOTS(VA7, 7)
        DOTS(VA8, 8)  DOTS(VA9, 9)  DOTS(VA10, 10) DOTS(VA11, 11)
        DOTS(VA12, 12) DOTS(VA13, 13) DOTS(VA14, 14) DOTS(VA15, 15)
#undef DOTS
        float u0 = (a0 + a1) + (a2 + a3);
        float u1 = (b0 + b1) + (b2 + b3);
        float y0 = ef0 * u0, y1 = ef1 * u1;    // y = 2^(A' - sh)

        float m = wavemax(fmaxf(y0, y1));      // exact max -> v' in (0,1]
        float rinv = __builtin_amdgcn_rcpf(m);
        vf0 = y0 * rinv; vf1 = y1 * rinv;
        vb[wv][lane] = pk16(vf0, vf1);         // same-wave DS is in-order
        sh += log2f(m);                        // exact bookkeeping, any m
        fcur = fnx;
    }

    // ---- epilogue: out = ln2 * log2 sum_j 2^(A_j + T2[EN][j]) ----
    float A0 = sh + log2f(vf0);                // log2(0) = -inf benign
    float A1e = sh + log2f(vf1);
    float w0 = fmaf(trans[(size_t)EN * TT + r0], L2E, A0);
    float w1 = fmaf(trans[(size_t)EN * TT + r1], L2E, A1e);
    float mm = wavemax(fmaxf(w0, w1));
    float e  = exp2f(w0 - mm) + exp2f(w1 - mm);
    float ssum = wavesum(e);
    if (lane == 0) out[b] = (mm + log2f(ssum)) * LN2f;
}

extern "C" void kernel_launch(void* const* d_in, const int* in_sizes, int n_in,
                              void* d_out, int out_size, void* d_ws, size_t ws_size,
                              hipStream_t stream) {
    const float* feats = (const float*)d_in[0];
    const int*   blen  = (const int*)d_in[1];
    const float* trans = (const float*)d_in[2];
    float*       o     = (float*)d_out;
    crf_fwd<<<dim3(BB / 4), dim3(256), 0, stream>>>(feats, blen, trans, o);
}

// Round 17
// 441.792 us; speedup vs baseline: 1.6846x; 1.6846x over previous
//
#include <hip/hip_runtime.h>

#define BB 256
#define SS 1024
#define TT 128
#define EN 127          // END state (row EN of trans = -1e4)
#define IMIN -10000.0f
#define L2E 1.4426950408889634f
#define LN2f 0.6931471805599453f

typedef _Float16 half2v __attribute__((ext_vector_type(2)));

__device__ __forceinline__ float fdot2(unsigned a, unsigned b, float c) {
    return __builtin_amdgcn_fdot2(__builtin_bit_cast(half2v, a),
                                  __builtin_bit_cast(half2v, b), c, false);
}
template<int CTRL>
__device__ __forceinline__ float dpp_mov(float x) {
    return __int_as_float(__builtin_amdgcn_update_dpp(
        0, __float_as_int(x), CTRL, 0xF, 0xF, true));
}
__device__ __forceinline__ float rl(float x, int l) {
    return __int_as_float(__builtin_amdgcn_readlane(__float_as_int(x), l));
}
// wave64 max/sum: 4 DPP stages (16-wide groups) + 4 readlane + combine (r16-proven)
__device__ __forceinline__ float wavemax(float x) {
    x = fmaxf(x, dpp_mov<0xB1>(x));    // quad xor1
    x = fmaxf(x, dpp_mov<0x4E>(x));    // quad xor2
    x = fmaxf(x, dpp_mov<0x141>(x));   // row_half_mirror
    x = fmaxf(x, dpp_mov<0x140>(x));   // row_mirror
    return fmaxf(fmaxf(rl(x, 0), rl(x, 16)), fmaxf(rl(x, 32), rl(x, 48)));
}
__device__ __forceinline__ float wavesum(float x) {
    x += dpp_mov<0xB1>(x);
    x += dpp_mov<0x4E>(x);
    x += dpp_mov<0x141>(x);
    x += dpp_mov<0x140>(x);
    return (rl(x, 0) + rl(x, 16)) + (rl(x, 32) + rl(x, 48));
}

// 2 waves (128 thr), ROW-PER-LANE: lane owns state r = wv*64+lane.
// P row = 64 packed f16x2 (64 VGPR); matvec = 64 v_dot2_f32_f16.
// v = 128 f16 in LDS (dbuf); 16 ds_read_b128 broadcast (64 VGPR dests --
// total ~160, no pressure, unlike r16's 192+ that forced re-reads).
// Lagged power-of-2 normalization: m = max(v_prev) via mbuf exchanged at
// the step barrier; m rounded to 2^k => rcp and log2 EXACT (zero drift);
// extra 2^-4 headroom keeps v' <= 2^15 < f16 max. No reduce on the chain.
// Features direct-global, prefetched 2 steps ahead; lgkm-only barrier
// keeps them in flight (r11/r13-proven).
__global__ __launch_bounds__(128, 1) void crf_fwd(const float* __restrict__ feats,
                                                  const int* __restrict__ blen,
                                                  const float* __restrict__ trans,
                                                  float* __restrict__ out)
{
    const int tid  = threadIdx.x;
    const int lane = tid & 63;
    const int wv   = tid >> 6;
    const int r    = tid;            // state row
    const int b    = blockIdx.x;

    __shared__ __align__(16) _Float16 vst[2][TT];
    __shared__ float mbuf[2][2];
    __shared__ float sred[2];

    const float* fb = feats + (size_t)b * (SS * TT);
    const int L = blen[b];

    // ---- init: P row -> 64 packed f16x2 (normalized 2^(T2-rm)), rowsum ----
    const float* tr = trans + (size_t)r * TT;
    float rm = -3.4e38f;
    #pragma unroll
    for (int k = 0; k < 32; ++k) {
        float4 t = ((const float4*)tr)[k];
        rm = fmaxf(rm, fmaxf(fmaxf(t.x, t.y), fmaxf(t.z, t.w)));
    }
    rm *= L2E;

    unsigned P[64];
    float S = 0.f;
    #pragma unroll
    for (int k = 0; k < 32; ++k) {
        float4 t = ((const float4*)tr)[k];
        float e0 = exp2f(fmaf(t.x, L2E, -rm)), e1 = exp2f(fmaf(t.y, L2E, -rm));
        float e2 = exp2f(fmaf(t.z, L2E, -rm)), e3 = exp2f(fmaf(t.w, L2E, -rm));
        S += (e0 + e1) + (e2 + e3);
        half2v h0; h0.x = (_Float16)e0; h0.y = (_Float16)e1;
        half2v h1; h1.x = (_Float16)e2; h1.y = (_Float16)e3;
        P[2 * k]     = __builtin_bit_cast(unsigned, h0);
        P[2 * k + 1] = __builtin_bit_cast(unsigned, h1);
    }

    // exact step 0 (alpha0 = delta on START, col START = -1e4):
    // A1 = f0*L2E + IMIN*L2E + rmc + log2(S*2^(rm-rmc) + 2^-rmc), rmc=max(rm,0)
    float f0 = fb[r];
    float rmc = fmaxf(rm, 0.f);
    float A1 = fmaf(f0, L2E, (IMIN * L2E) + rmc +
                    log2f(fmaf(S, exp2f(rm - rmc), exp2f(-rmc))));

    float wm = wavemax(A1);
    if (lane == 0) mbuf[0][wv] = wm;
    __syncthreads();
    float m0 = fmaxf(mbuf[0][0], mbuf[0][1]);
    float sh = m0;
    float vf = exp2f(A1 - m0);            // <= 1
    vst[0][r] = (_Float16)vf;
    float wmv = wavemax(vf);              // max v for step-1 normalization
    if (lane == 0) mbuf[0][wv] = wmv;
    __syncthreads();

    int cur = 0;
    float fA = fb[TT + r];                              // feat for step 1
    float fB = fb[(size_t)((2 < SS) ? 2 : SS - 1) * TT + r];

    for (int s = 1; s < L; ++s) {
        int sp = s + 2; sp = (sp < SS) ? sp : SS - 1;
        float fC = fb[(size_t)sp * TT + r];             // prefetch 2 ahead

        // lagged max -> power-of-2 (exact rcp & log): extra 2^-4 headroom
        float m = fmaxf(mbuf[cur][0], mbuf[cur][1]);
        unsigned e = __float_as_uint(m) >> 23;          // biased exponent
        float rinv = __uint_as_float((250u - e) << 23); // 2^-(e-127)-4
        float dsh = (float)(int)(e - 123u);             // (e-127)+4

        // broadcast-read whole v (16 x b128); dests ~64 VGPR, held easily
        const uint4* vv = (const uint4*)vst[cur];
        uint4 V0 = vv[0],  V1 = vv[1],  V2 = vv[2],  V3 = vv[3];
        uint4 V4 = vv[4],  V5 = vv[5],  V6 = vv[6],  V7 = vv[7];
        uint4 V8 = vv[8],  V9 = vv[9],  V10 = vv[10], V11 = vv[11];
        uint4 V12 = vv[12], V13 = vv[13], V14 = vv[14], V15 = vv[15];

        float ef  = exp2f(fmaf(fA, L2E, rm));
        float cfm = ef * rinv;

        float a0 = 0.f, a1 = 0.f, a2 = 0.f, a3 = 0.f;
        float a4 = 0.f, a5 = 0.f, a6 = 0.f, a7 = 0.f;
#define D4(Vq, q) \
        a0 = fdot2(P[4*(q)+0], Vq.x, a0); a1 = fdot2(P[4*(q)+1], Vq.y, a1); \
        a2 = fdot2(P[4*(q)+2], Vq.z, a2); a3 = fdot2(P[4*(q)+3], Vq.w, a3);
#define D4b(Vq, q) \
        a4 = fdot2(P[4*(q)+0], Vq.x, a4); a5 = fdot2(P[4*(q)+1], Vq.y, a5); \
        a6 = fdot2(P[4*(q)+2], Vq.z, a6); a7 = fdot2(P[4*(q)+3], Vq.w, a7);
        D4(V0, 0)   D4b(V1, 1)  D4(V2, 2)   D4b(V3, 3)
        D4(V4, 4)   D4b(V5, 5)  D4(V6, 6)   D4b(V7, 7)
        D4(V8, 8)   D4b(V9, 9)  D4(V10, 10) D4b(V11, 11)
        D4(V12, 12) D4b(V13, 13) D4(V14, 14) D4b(V15, 15)
#undef D4
#undef D4b
        float tot = ((a0 + a4) + (a1 + a5)) + ((a2 + a6) + (a3 + a7));
        float vn  = cfm * tot;              // row EN: ef==0 -> vn=0, benign
        sh += dsh;
        vst[cur ^ 1][r] = (_Float16)vn;     // RNE
        float wmx = wavemax(vn);
        if (lane == 0) mbuf[cur ^ 1][wv] = wmx;
        // lgkm-only barrier: global prefetches stay in flight
        asm volatile("s_waitcnt lgkmcnt(0)\n\ts_barrier" ::: "memory");
        cur ^= 1;
        vf = vn;
        fA = fB; fB = fC;
    }

    // ---- epilogue: out = ln2 * log2 sum_j 2^(sh + log2 v_j + T2[EN][j]) ----
    float te = trans[(size_t)EN * TT + r];
    float A  = sh + log2f(vf);              // v=0 -> -inf, benign
    float w  = fmaf(te, L2E, A);
    float wmm = wavemax(w);
    if (lane == 0) mbuf[0][wv] = wmm;
    __syncthreads();
    float mm = fmaxf(mbuf[0][0], mbuf[0][1]);
    float ee = exp2f(w - mm);
    float se = wavesum(ee);
    if (lane == 0) sred[wv] = se;
    __syncthreads();
    if (tid == 0) out[b] = (mm + log2f(sred[0] + sred[1])) * LN2f;
}

extern "C" void kernel_launch(void* const* d_in, const int* in_sizes, int n_in,
                              void* d_out, int out_size, void* d_ws, size_t ws_size,
                              hipStream_t stream) {
    const float* feats = (const float*)d_in[0];
    const int*   blen  = (const int*)d_in[1];
    const float* trans = (const float*)d_in[2];
    float*       o     = (float*)d_out;
    crf_fwd<<<dim3(BB), dim3(128), 0, stream>>>(feats, blen, trans, o);
}